// Round 1
// baseline (270.212 us; speedup 1.0000x reference)
//
#include <hip/hip_runtime.h>

typedef unsigned short u16;
typedef unsigned int   u32;
typedef __bf16   bf16x8 __attribute__((ext_vector_type(8)));
typedef float    f32x4  __attribute__((ext_vector_type(4)));
typedef u16      u16x4  __attribute__((ext_vector_type(4)));
typedef u16      u16x8  __attribute__((ext_vector_type(8)));
typedef u32      u32x2  __attribute__((ext_vector_type(2)));
typedef u32      u32x4  __attribute__((ext_vector_type(4)));

#if __has_builtin(__builtin_amdgcn_exp2f)
#define EXP2(x) __builtin_amdgcn_exp2f(x)
#else
#define EXP2(x) exp2f(x)
#endif

// fp32 -> bf16 round-to-nearest-even
__device__ __forceinline__ u16 f2bf(float f) {
    unsigned u = __float_as_uint(f);
    u += 0x7FFFu + ((u >> 16) & 1u);
    return (u16)(u >> 16);
}

__device__ __forceinline__ u32 pack_bf16(float a, float b) {
#if __has_builtin(__builtin_amdgcn_cvt_pk_bf16_f32)
    typedef __bf16 bf16x2 __attribute__((ext_vector_type(2)));
    bf16x2 r = __builtin_amdgcn_cvt_pk_bf16_f32(a, b);
    return __builtin_bit_cast(u32, r);
#else
    return (u32)f2bf(a) | ((u32)f2bf(b) << 16);
#endif
}

// async global->LDS, 16 bytes/lane. LDS dest = wave-uniform base + lane*16.
__device__ __forceinline__ void async_copy16(const u16* g, u16* l) {
    __builtin_amdgcn_global_load_lds(
        (const __attribute__((address_space(1))) unsigned*)g,
        (__attribute__((address_space(3))) unsigned*)l, 16, 0, 0);
}

__device__ __forceinline__ bf16x8 lds_frag(const u16* p) {
    return *(const bf16x8*)p;
}

// gfx950 cross-lane swaps (both operands read-write).
// permlane32: new a[i<32]=a, a[i>=32]=b[i-32]; new b[i<32]=a[i+32], b[i>=32]=b
// permlane16: same with 16-rows inside each 32-half.
__device__ __forceinline__ void permlane32_swap(u32& a, u32& b) {
    asm("v_permlane32_swap_b32 %0, %1" : "+v"(a), "+v"(b));
}
__device__ __forceinline__ void permlane16_swap(u32& a, u32& b) {
    asm("v_permlane16_swap_b32 %0, %1" : "+v"(a), "+v"(b));
}

// ---------------------------------------------------------------------------
// Fused prep: blocks [0,768) transpose Wqkv, [768,1024) transpose Wout,
// [1024,5120) convert x to bf16 (16 elems/thread).
__global__ __launch_bounds__(256) void prep(const float* __restrict__ x,
                                            const float* __restrict__ Wqkv,
                                            const float* __restrict__ Wout,
                                            u16* __restrict__ xb,
                                            u16* __restrict__ wqkv_t,
                                            u16* __restrict__ wout_t) {
    __shared__ u16 t[64 * 72];
    const int bid = blockIdx.x;
    const int tid = threadIdx.x;

    if (bid >= 1024) {
        // x fp32 -> bf16
        size_t i = ((size_t)(bid - 1024) * 256 + tid) * 8;
        float4 v0 = *(const float4*)(x + i);
        float4 v1 = *(const float4*)(x + i + 4);
        u16x8 o = { f2bf(v0.x), f2bf(v0.y), f2bf(v0.z), f2bf(v0.w),
                    f2bf(v1.x), f2bf(v1.y), f2bf(v1.z), f2bf(v1.w) };
        *(u16x8*)(xb + i) = o;
        return;
    }

    // W fp32 [Kd][Nd] -> Wt bf16 [Nd][Kd]
    const float* W;  u16* Wt;  int Kd, Nd, n0, k0;
    if (bid < 768) { W = Wqkv; Wt = wqkv_t; Kd = 1024; Nd = 3072;
                     n0 = (bid % 48) * 64; k0 = (bid / 48) * 64; }
    else           { W = Wout; Wt = wout_t; Kd = 1024; Nd = 1024;
                     n0 = ((bid - 768) % 16) * 64; k0 = ((bid - 768) / 16) * 64; }
#pragma unroll
    for (int i = 0; i < 4; ++i) {
        int lin = i * 256 + tid;
        int kr = lin >> 4, nc = (lin & 15) << 2;
        float4 v = *(const float4*)(W + (size_t)(k0 + kr) * Nd + n0 + nc);
        u16x4 o = { f2bf(v.x), f2bf(v.y), f2bf(v.z), f2bf(v.w) };
        *(u16x4*)&t[kr * 72 + nc] = o;
    }
    __syncthreads();
#pragma unroll
    for (int i = 0; i < 2; ++i) {
        int lin = i * 256 + tid;
        int nr = lin >> 3, kc = (lin & 7) << 3;
        u16x8 o;
#pragma unroll
        for (int jj = 0; jj < 8; ++jj) o[jj] = t[(kc + jj) * 72 + nr];
        *(u16x8*)(Wt + (size_t)(n0 + nr) * Kd + k0 + kc) = o;
    }
}

// ---------------------------------------------------------------------------
// QKV gemm: C[M,N] = A[M,K] * Bt[N,K]^T, 128x128 tile, BK=32, double-buffered
// (one barrier/iter), LDS chunk-XOR swizzle (conflict-free, verified R6).
// Scatter epilogue: Q (scaled by 0.125*log2e) [bh][l][64], K [bh][l][64],
// V transposed [bh][kd][2048].
__global__ __launch_bounds__(256) void gemm_qkv(const u16* __restrict__ A,
                                                const u16* __restrict__ Bt,
                                                u16* __restrict__ outb,
                                                int K, int N) {
    __shared__ u16 As[2][128 * 32];
    __shared__ u16 Bs[2][128 * 32];
    const int tid = threadIdx.x;
    const int lane = tid & 63;
    const int wv = tid >> 6;
    const int wr = (wv >> 1) * 64;
    const int wc = (wv & 1) * 64;
    const int qd = lane >> 4;
    const int c  = lane & 15;
    const int m0 = blockIdx.y * 128;
    const int n0 = blockIdx.x * 128;

    const int srow = tid >> 2;
    const int sg = ((tid & 3) ^ ((srow >> 1) & 3)) << 3;   // swizzled source chunk

    const u16* Ag0 = A  + (size_t)(m0 +      srow) * K + sg;
    const u16* Ag1 = A  + (size_t)(m0 + 64 + srow) * K + sg;
    const u16* Bg0 = Bt + (size_t)(n0 +      srow) * K + sg;
    const u16* Bg1 = Bt + (size_t)(n0 + 64 + srow) * K + sg;

    const u32 fsw = (qd ^ ((c >> 1) & 3)) << 3;            // swizzled frag chunk
    const u32 a_off = (wr + c) * 32 + fsw;                 // + i*512
    const u32 b_off = (wc + c) * 32 + fsw;                 // + j*512

    f32x4 acc[4][4] = {};

    async_copy16(Ag0, &As[0][tid * 8]);
    async_copy16(Ag1, &As[0][2048 + tid * 8]);
    async_copy16(Bg0, &Bs[0][tid * 8]);
    async_copy16(Bg1, &Bs[0][2048 + tid * 8]);

    int p = 0;
    for (int k0 = 0; k0 < K; k0 += 32) {
        __syncthreads();
        if (k0 + 32 < K) {
            const int np = p ^ 1;
            async_copy16(Ag0 + k0 + 32, &As[np][tid * 8]);
            async_copy16(Ag1 + k0 + 32, &As[np][2048 + tid * 8]);
            async_copy16(Bg0 + k0 + 32, &Bs[np][tid * 8]);
            async_copy16(Bg1 + k0 + 32, &Bs[np][2048 + tid * 8]);
        }
        bf16x8 af[4], bfr[4];
#pragma unroll
        for (int i = 0; i < 4; ++i) af[i]  = lds_frag(&As[p][a_off + i * 512]);
#pragma unroll
        for (int j = 0; j < 4; ++j) bfr[j] = lds_frag(&Bs[p][b_off + j * 512]);
#pragma unroll
        for (int i = 0; i < 4; ++i)
#pragma unroll
            for (int j = 0; j < 4; ++j)
                acc[i][j] = __builtin_amdgcn_mfma_f32_16x16x32_bf16(af[i], bfr[j], acc[i][j], 0, 0, 0);
        p ^= 1;
    }

    // C/D layout: col = lane&15, row = (lane>>4)*4 + reg
#pragma unroll
    for (int i = 0; i < 4; ++i)
#pragma unroll
        for (int j = 0; j < 4; ++j) {
            int n = n0 + wc + j * 16 + c;
            int which = n >> 10, h = (n >> 6) & 15, kd = n & 63;
            int m_base = m0 + wr + i * 16 + qd * 4;
            int b = m_base >> 11, l0 = m_base & 2047;
            int bh = b * 16 + h;
            if (which == 2) {
                u32x2 o2;
                o2[0] = pack_bf16(acc[i][j][0], acc[i][j][1]);
                o2[1] = pack_bf16(acc[i][j][2], acc[i][j][3]);
                *(u32x2*)(outb + (size_t)(128 + bh) * 131072 + (size_t)kd * 2048 + l0) = o2;
            } else if (which == 0) {
#pragma unroll
                for (int r = 0; r < 4; ++r)
                    outb[(size_t)bh * 131072 + (size_t)(l0 + r) * 64 + kd] =
                        f2bf(acc[i][j][r] * 0.1803368801f);   // 0.125*log2(e)
            } else {
#pragma unroll
                for (int r = 0; r < 4; ++r)
                    outb[(size_t)(64 + bh) * 131072 + (size_t)(l0 + r) * 64 + kd] =
                        f2bf(acc[i][j][r]);
            }
        }
}

// ---------------------------------------------------------------------------
// Output gemm: C[M,N] fp32 = A[M,K]bf16 * Bt[N,K]^T. 64x128 tile, BK=32,
// double-buffered, swizzled. Grid (8,128) -> 1024 blocks = 4 blocks/CU.
__global__ __launch_bounds__(256) void gemm_out(const u16* __restrict__ A,
                                                const u16* __restrict__ Bt,
                                                float* __restrict__ outf,
                                                int K, int N) {
    __shared__ u16 As[2][64 * 32];
    __shared__ u16 Bs[2][128 * 32];
    const int tid = threadIdx.x;
    const int lane = tid & 63;
    const int wv = tid >> 6;
    const int wr = (wv >> 1) * 32;     // wave row-half: 0 or 32
    const int wc = (wv & 1) * 64;      // wave col-half: 0 or 64
    const int qd = lane >> 4;
    const int c  = lane & 15;
    const int m0 = blockIdx.y * 64;
    const int n0 = blockIdx.x * 128;

    const int srow = tid >> 2;         // 0..63
    const int sg = ((tid & 3) ^ ((srow >> 1) & 3)) << 3;

    const u16* Ag0 = A  + (size_t)(m0 +      srow) * K + sg;   // 64 rows, 1 issue
    const u16* Bg0 = Bt + (size_t)(n0 +      srow) * K + sg;
    const u16* Bg1 = Bt + (size_t)(n0 + 64 + srow) * K + sg;

    const u32 fsw = (qd ^ ((c >> 1) & 3)) << 3;
    const u32 a_off = (wr + c) * 32 + fsw;                 // + i*512
    const u32 b_off = (wc + c) * 32 + fsw;                 // + j*512

    f32x4 acc[2][4] = {};

    async_copy16(Ag0, &As[0][tid * 8]);
    async_copy16(Bg0, &Bs[0][tid * 8]);
    async_copy16(Bg1, &Bs[0][2048 + tid * 8]);

    int p = 0;
    for (int k0 = 0; k0 < K; k0 += 32) {
        __syncthreads();
        if (k0 + 32 < K) {
            const int np = p ^ 1;
            async_copy16(Ag0 + k0 + 32, &As[np][tid * 8]);
            async_copy16(Bg0 + k0 + 32, &Bs[np][tid * 8]);
            async_copy16(Bg1 + k0 + 32, &Bs[np][2048 + tid * 8]);
        }
        bf16x8 af[2], bfr[4];
#pragma unroll
        for (int i = 0; i < 2; ++i) af[i]  = lds_frag(&As[p][a_off + i * 512]);
#pragma unroll
        for (int j = 0; j < 4; ++j) bfr[j] = lds_frag(&Bs[p][b_off + j * 512]);
#pragma unroll
        for (int i = 0; i < 2; ++i)
#pragma unroll
            for (int j = 0; j < 4; ++j)
                acc[i][j] = __builtin_amdgcn_mfma_f32_16x16x32_bf16(af[i], bfr[j], acc[i][j], 0, 0, 0);
        p ^= 1;
    }

#pragma unroll
    for (int i = 0; i < 2; ++i)
#pragma unroll
        for (int j = 0; j < 4; ++j)
#pragma unroll
            for (int r = 0; r < 4; ++r) {
                int m = m0 + wr + i * 16 + qd * 4 + r;
                int n = n0 + wc + j * 16 + c;
                outf[(size_t)m * N + n] = acc[i][j][r];
            }
}

// ---------------------------------------------------------------------------
// Flash attention, causal, S^T form. NEW this round:
//  * 2-deep S pipeline: QK^T MFMAs of tile kt+1 are issued BEFORE the
//    softmax/PV of tile kt, so the exp2-heavy VALU phase executes under
//    in-flight MFMAs (within-wave MFMA||VALU overlap).
//  * P^T redistribution fully in-register via v_permlane{32,16}_swap_b32
//    (replaces the per-wave LDS round-trip; Ps buffer removed).
//  * exp2 bias (-8) folded into the MFMA C-initializer; row-sums
//    accumulated as f32x4 (v_pk_add_f32).
//  * V triple-buffered (PV lags one tile): LDS = 2*16K (K) + 3*16K (V)
//    = 80 KB -> still exactly 2 blocks/CU.
__global__ __launch_bounds__(256, 2) void attn_kernel(const u16* __restrict__ qkv,
                                                      u16* __restrict__ att) {
    __shared__ u16 Ks[2][128 * 64];   // [key][kd], 16B-chunk XOR swizzled
    __shared__ u16 Vt[3][64 * 128];   // [kd][key], 16B-chunk XOR swizzled

    const int tid = threadIdx.x;
    const int lane = tid & 63;
    const int w = tid >> 6;
    const int qd = lane >> 4;
    const int c = lane & 15;

    // XCD swizzle: flat%8 == bh%8 -> one bh's K/V stays in one XCD L2
    const int flat = blockIdx.x + 8 * blockIdx.y;
    const int bh = (flat & 7) + 8 * ((flat >> 3) & 7);
    const int bx = flat >> 6;
    const int b = bh >> 4, h = bh & 15;

    const u16* Qg = qkv + (size_t)bh * 131072;
    const u16* Kg = qkv + (size_t)(64 + bh) * 131072;
    const u16* Vg = qkv + (size_t)(128 + bh) * 131072;   // [kd][2048]

    u32 kf_off[2];
#pragma unroll
    for (int ks = 0; ks < 2; ++ks)
        kf_off[ks] = c * 64 + (((ks * 4 + qd) ^ (c & 7)) << 3);
    u32 vf_off[4];
#pragma unroll
    for (int kc = 0; kc < 4; ++kc)
        vf_off[kc] = c * 128 + (((kc * 4 + qd) ^ c) << 3);

    // 8 x 16B async copies per tile (K and V), pre-swizzled global source,
    // linear LDS dest (global_load_lds requirement).
    auto issue_copy = [&](int t, u16* kd, u16* vd) {
#pragma unroll
        for (int it = 0; it < 4; ++it) {
            int lin = it * 256 + tid;
            int krw = lin >> 3, kch = lin & 7;
            int vrw = lin >> 4, vch = lin & 15;
            async_copy16(Kg + (size_t)t * 8192 + krw * 64 + ((kch ^ (krw & 7)) << 3),
                         kd + lin * 8);
            async_copy16(Vg + (size_t)t * 128 + (size_t)vrw * 2048 + ((vch ^ (vrw & 15)) << 3),
                         vd + lin * 8);
        }
    };

#pragma unroll 1
    for (int seg = 0; seg < 2; ++seg) {
        const int qt = seg ? (15 - bx) : bx;            // balanced causal pairing
        const int qa_row = qt * 128 + w * 32 + c;       // frag a
        const int qb_row = qa_row + 16;                 // frag b

        bf16x8 qa[2], qb[2];
#pragma unroll
        for (int ks = 0; ks < 2; ++ks) {
            qa[ks] = *(const bf16x8*)(Qg + (size_t)qa_row * 64 + ks * 32 + qd * 8);
            qb[ks] = *(const bf16x8*)(Qg + (size_t)qb_row * 64 + ks * 32 + qd * 8);
        }

        f32x4 acca[4] = {}, accb[4] = {};
        f32x4 rva = {}, rvb = {};                        // packed row-sum accum
        f32x4 saA[8], sbA[8], saB[8], sbB[8];            // two S register sets

        const int nkt = qt + 1;

        // S^T = K Q^T for one tile; C initialized to -8 (softmax bias folded).
        auto compute_S = [&](const u16* ksb, f32x4* sa, f32x4* sb) {
#pragma unroll
            for (int f = 0; f < 8; ++f) {
                sa[f] = f32x4{-8.f, -8.f, -8.f, -8.f};
                sb[f] = f32x4{-8.f, -8.f, -8.f, -8.f};
            }
            __builtin_amdgcn_s_setprio(1);
#pragma unroll
            for (int ks = 0; ks < 2; ++ks) {
                const u16* kp = ksb + kf_off[ks];
#pragma unroll
                for (int f = 0; f < 8; ++f) {
                    bf16x8 kf = lds_frag(kp + f * 1024);
                    sa[f] = __builtin_amdgcn_mfma_f32_16x16x32_bf16(kf, qa[ks], sa[f], 0, 0, 0);
                    sb[f] = __builtin_amdgcn_mfma_f32_16x16x32_bf16(kf, qb[ks], sb[f], 0, 0, 0);
                }
            }
            __builtin_amdgcn_s_setprio(0);
        };

        // mask + exp2 + row-sums + in-register P^T redistribution + PV
        auto finish_tile = [&](int kt, f32x4* sa, f32x4* sb, const u16* vtb) {
            if (kt == qt) {
#pragma unroll
                for (int f = 0; f < 8; ++f)
#pragma unroll
                    for (int r = 0; r < 4; ++r) {
                        int key = kt * 128 + f * 16 + qd * 4 + r;
                        if (key > qa_row) sa[f][r] = -3e38f;
                        if (key > qb_row) sb[f][r] = -3e38f;
                    }
            }
#pragma unroll
            for (int f = 0; f < 8; ++f) {
#pragma unroll
                for (int r = 0; r < 4; ++r) {
                    sa[f][r] = EXP2(sa[f][r]);
                    sb[f][r] = EXP2(sb[f][r]);
                }
                rva += sa[f];                            // v_pk_add_f32 x2
                rvb += sb[f];
            }
            // Per 32-key slab kc: source lane holds keys f*16+qd*4+{0..3};
            // B-frag wants keys kc*32+qd*8+{0..7}. One permlane32_swap +
            // one permlane16_swap per u32-pair lands exactly the right words.
#pragma unroll
            for (int kc = 0; kc < 4; ++kc) {
                u32 a0 = pack_bf16(sa[2 * kc][0], sa[2 * kc][1]);
                u32 a1 = pack_bf16(sa[2 * kc + 1][0], sa[2 * kc + 1][1]);
                u32 b0 = pack_bf16(sa[2 * kc][2], sa[2 * kc][3]);
                u32 b1 = pack_bf16(sa[2 * kc + 1][2], sa[2 * kc + 1][3]);
                permlane32_swap(a0, a1); permlane16_swap(a0, a1);
                permlane32_swap(b0, b1); permlane16_swap(b0, b1);
                u32x4 wa = {a0, b0, a1, b1};
                u32 c0 = pack_bf16(sb[2 * kc][0], sb[2 * kc][1]);
                u32 c1 = pack_bf16(sb[2 * kc + 1][0], sb[2 * kc + 1][1]);
                u32 d0 = pack_bf16(sb[2 * kc][2], sb[2 * kc][3]);
                u32 d1 = pack_bf16(sb[2 * kc + 1][2], sb[2 * kc + 1][3]);
                permlane32_swap(c0, c1); permlane16_swap(c0, c1);
                permlane32_swap(d0, d1); permlane16_swap(d0, d1);
                u32x4 wb = {c0, d0, c1, d1};
                bf16x8 pa = __builtin_bit_cast(bf16x8, wa);
                bf16x8 pb = __builtin_bit_cast(bf16x8, wb);
                const u16* vp = vtb + vf_off[kc];
                __builtin_amdgcn_s_setprio(1);
#pragma unroll
                for (int jo = 0; jo < 4; ++jo) {
                    bf16x8 vf = lds_frag(vp + jo * 2048);
                    acca[jo] = __builtin_amdgcn_mfma_f32_16x16x32_bf16(vf, pa, acca[jo], 0, 0, 0);
                    accb[jo] = __builtin_amdgcn_mfma_f32_16x16x32_bf16(vf, pb, accb[jo], 0, 0, 0);
                }
                __builtin_amdgcn_s_setprio(0);
            }
        };

        // ---- prologue: tile 0 staged, S(0) issued, tile 1 in flight ----
        __syncthreads();                     // prev-seg readers done
        issue_copy(0, Ks[0], Vt[0]);
        __syncthreads();                     // tile 0 ready (all waves)
        if (nkt > 1) issue_copy(1, Ks[1], Vt[1]);
        compute_S(Ks[0], saA, sbA);

        u16 *vPV = Vt[0], *vNx = Vt[1], *vFr = Vt[2];

        int kt = 0;
        for (;;) {
            {   // even body: current tile kt (set A)
                const bool last = (kt + 1 >= nkt);
                if (!last) {
                    __syncthreads();                         // tile kt+1 ready; kt-1 bufs free
                    if (kt + 2 < nkt) issue_copy(kt + 2, Ks[0], vFr);
                    compute_S(Ks[1], saB, sbB);              // MFMAs overlap finish below
                }
                finish_tile(kt, saA, sbA, vPV);
                if (last) break;
                u16* t0 = vPV; vPV = vNx; vNx = vFr; vFr = t0;
            }
            {   // odd body: current tile kt+1 (set B)
                const bool last = (kt + 2 >= nkt);
                if (!last) {
                    __syncthreads();
                    if (kt + 3 < nkt) issue_copy(kt + 3, Ks[1], vFr);
                    compute_S(Ks[0], saA, sbA);
                }
                finish_tile(kt + 1, saB, sbB, vPV);
                if (last) break;
                u16* t0 = vPV; vPV = vNx; vNx = vFr; vFr = t0;
            }
            kt += 2;
        }

        // epilogue: reduce row-sums across the 4 quad-groups, then scale
        float ra = rva[0] + rva[1] + rva[2] + rva[3];
        float rb = rvb[0] + rvb[1] + rvb[2] + rvb[3];
        ra += __shfl_xor(ra, 16, 64);
        ra += __shfl_xor(ra, 32, 64);
        rb += __shfl_xor(rb, 16, 64);
        rb += __shfl_xor(rb, 32, 64);
        float ia = __builtin_amdgcn_rcpf(ra), ib = __builtin_amdgcn_rcpf(rb);
        u16* ar = att + ((size_t)b * 2048 + qa_row) * 1024 + h * 64;
        u16* br = att + ((size_t)b * 2048 + qb_row) * 1024 + h * 64;
#pragma unroll
        for (int jo = 0; jo < 4; ++jo) {
            u32x2 oa, ob;
            oa[0] = pack_bf16(acca[jo][0] * ia, acca[jo][1] * ia);
            oa[1] = pack_bf16(acca[jo][2] * ia, acca[jo][3] * ia);
            ob[0] = pack_bf16(accb[jo][0] * ib, accb[jo][1] * ib);
            ob[1] = pack_bf16(accb[jo][2] * ib, accb[jo][3] * ib);
            *(u32x2*)(ar + jo * 16 + qd * 4) = oa;
            *(u32x2*)(br + jo * 16 + qd * 4) = ob;
        }
    }
}

// ---------------------------------------------------------------------------
extern "C" void kernel_launch(void* const* d_in, const int* in_sizes, int n_in,
                              void* d_out, int out_size, void* d_ws, size_t ws_size,
                              hipStream_t stream) {
    const float* x    = (const float*)d_in[0];   // [4,2048,1024]
    const float* Wqkv = (const float*)d_in[1];   // [1024,3072]
    const float* Wout = (const float*)d_in[2];   // [1024,1024]
    float* out = (float*)d_out;                  // [4,2048,1024] fp32

    char* ws = (char*)d_ws;
    u16* x_bf   = (u16*)(ws);                    // 16 MB
    u16* wqkv_t = (u16*)(ws + 16777216);         // 6 MB   [3072][1024]
    u16* wout_t = (u16*)(ws + 23068672);         // 2 MB   [1024][1024]
    u16* qkv_h  = (u16*)(ws + 25165824);         // 48 MB  Q,K [bh][l][64], V^T [bh][kd][2048]
    u16* att    = (u16*)(ws + 75497472);         // 16 MB  [4][2048][1024]

    prep<<<dim3(5120), dim3(256), 0, stream>>>(x, Wqkv, Wout, x_bf, wqkv_t, wout_t);
    gemm_qkv<<<dim3(24, 64), dim3(256), 0, stream>>>(x_bf, wqkv_t, qkv_h, 1024, 3072);
    attn_kernel<<<dim3(8, 64), dim3(256), 0, stream>>>(qkv_h, att);
    gemm_out<<<dim3(8, 128), dim3(256), 0, stream>>>(att, wout_t, out, 1024, 1024);
}

// Round 2
// 250.340 us; speedup vs baseline: 1.0794x; 1.0794x over previous
//
#include <hip/hip_runtime.h>

typedef unsigned short u16;
typedef unsigned int   u32;
typedef __bf16   bf16x8 __attribute__((ext_vector_type(8)));
typedef float    f32x4  __attribute__((ext_vector_type(4)));
typedef u16      u16x4  __attribute__((ext_vector_type(4)));
typedef u16      u16x8  __attribute__((ext_vector_type(8)));
typedef u32      u32x2  __attribute__((ext_vector_type(2)));
typedef u32      u32x4  __attribute__((ext_vector_type(4)));

#if __has_builtin(__builtin_amdgcn_exp2f)
#define EXP2(x) __builtin_amdgcn_exp2f(x)
#else
#define EXP2(x) exp2f(x)
#endif

// fp32 -> bf16 round-to-nearest-even
__device__ __forceinline__ u16 f2bf(float f) {
    unsigned u = __float_as_uint(f);
    u += 0x7FFFu + ((u >> 16) & 1u);
    return (u16)(u >> 16);
}

__device__ __forceinline__ u32 pack_bf16(float a, float b) {
#if __has_builtin(__builtin_amdgcn_cvt_pk_bf16_f32)
    typedef __bf16 bf16x2 __attribute__((ext_vector_type(2)));
    bf16x2 r = __builtin_amdgcn_cvt_pk_bf16_f32(a, b);
    return __builtin_bit_cast(u32, r);
#else
    return (u32)f2bf(a) | ((u32)f2bf(b) << 16);
#endif
}

// async global->LDS, 16 bytes/lane. LDS dest = wave-uniform base + lane*16.
__device__ __forceinline__ void async_copy16(const u16* g, u16* l) {
    __builtin_amdgcn_global_load_lds(
        (const __attribute__((address_space(1))) unsigned*)g,
        (__attribute__((address_space(3))) unsigned*)l, 16, 0, 0);
}

__device__ __forceinline__ bf16x8 lds_frag(const u16* p) {
    return *(const bf16x8*)p;
}

// gfx950 cross-lane swaps (both operands read-write).
__device__ __forceinline__ void permlane32_swap(u32& a, u32& b) {
    asm("v_permlane32_swap_b32 %0, %1" : "+v"(a), "+v"(b));
}
__device__ __forceinline__ void permlane16_swap(u32& a, u32& b) {
    asm("v_permlane16_swap_b32 %0, %1" : "+v"(a), "+v"(b));
}

// ---------------------------------------------------------------------------
// Fused prep: blocks [0,768) transpose Wqkv, [768,1024) transpose Wout,
// [1024,5120) convert x to bf16 (16 elems/thread).
__global__ __launch_bounds__(256) void prep(const float* __restrict__ x,
                                            const float* __restrict__ Wqkv,
                                            const float* __restrict__ Wout,
                                            u16* __restrict__ xb,
                                            u16* __restrict__ wqkv_t,
                                            u16* __restrict__ wout_t) {
    __shared__ u16 t[64 * 72];
    const int bid = blockIdx.x;
    const int tid = threadIdx.x;

    if (bid >= 1024) {
        // x fp32 -> bf16
        size_t i = ((size_t)(bid - 1024) * 256 + tid) * 8;
        float4 v0 = *(const float4*)(x + i);
        float4 v1 = *(const float4*)(x + i + 4);
        u16x8 o = { f2bf(v0.x), f2bf(v0.y), f2bf(v0.z), f2bf(v0.w),
                    f2bf(v1.x), f2bf(v1.y), f2bf(v1.z), f2bf(v1.w) };
        *(u16x8*)(xb + i) = o;
        return;
    }

    // W fp32 [Kd][Nd] -> Wt bf16 [Nd][Kd]
    const float* W;  u16* Wt;  int Kd, Nd, n0, k0;
    if (bid < 768) { W = Wqkv; Wt = wqkv_t; Kd = 1024; Nd = 3072;
                     n0 = (bid % 48) * 64; k0 = (bid / 48) * 64; }
    else           { W = Wout; Wt = wout_t; Kd = 1024; Nd = 1024;
                     n0 = ((bid - 768) % 16) * 64; k0 = ((bid - 768) / 16) * 64; }
#pragma unroll
    for (int i = 0; i < 4; ++i) {
        int lin = i * 256 + tid;
        int kr = lin >> 4, nc = (lin & 15) << 2;
        float4 v = *(const float4*)(W + (size_t)(k0 + kr) * Nd + n0 + nc);
        u16x4 o = { f2bf(v.x), f2bf(v.y), f2bf(v.z), f2bf(v.w) };
        *(u16x4*)&t[kr * 72 + nc] = o;
    }
    __syncthreads();
#pragma unroll
    for (int i = 0; i < 2; ++i) {
        int lin = i * 256 + tid;
        int nr = lin >> 3, kc = (lin & 7) << 3;
        u16x8 o;
#pragma unroll
        for (int jj = 0; jj < 8; ++jj) o[jj] = t[(kc + jj) * 72 + nr];
        *(u16x8*)(Wt + (size_t)(n0 + nr) * Kd + k0 + kc) = o;
    }
}

// ---------------------------------------------------------------------------
// QKV gemm: C[M,N] = A[M,K] * Bt[N,K]^T, 128x128 tile, BK=32, double-buffered
// (one barrier/iter), LDS chunk-XOR swizzle (conflict-free, verified R6).
// Scatter epilogue: Q (scaled by 0.125*log2e) [bh][l][64], K [bh][l][64],
// V transposed [bh][kd][2048].
__global__ __launch_bounds__(256) void gemm_qkv(const u16* __restrict__ A,
                                                const u16* __restrict__ Bt,
                                                u16* __restrict__ outb,
                                                int K, int N) {
    __shared__ u16 As[2][128 * 32];
    __shared__ u16 Bs[2][128 * 32];
    const int tid = threadIdx.x;
    const int lane = tid & 63;
    const int wv = tid >> 6;
    const int wr = (wv >> 1) * 64;
    const int wc = (wv & 1) * 64;
    const int qd = lane >> 4;
    const int c  = lane & 15;
    const int m0 = blockIdx.y * 128;
    const int n0 = blockIdx.x * 128;

    const int srow = tid >> 2;
    const int sg = ((tid & 3) ^ ((srow >> 1) & 3)) << 3;   // swizzled source chunk

    const u16* Ag0 = A  + (size_t)(m0 +      srow) * K + sg;
    const u16* Ag1 = A  + (size_t)(m0 + 64 + srow) * K + sg;
    const u16* Bg0 = Bt + (size_t)(n0 +      srow) * K + sg;
    const u16* Bg1 = Bt + (size_t)(n0 + 64 + srow) * K + sg;

    const u32 fsw = (qd ^ ((c >> 1) & 3)) << 3;            // swizzled frag chunk
    const u32 a_off = (wr + c) * 32 + fsw;                 // + i*512
    const u32 b_off = (wc + c) * 32 + fsw;                 // + j*512

    f32x4 acc[4][4] = {};

    async_copy16(Ag0, &As[0][tid * 8]);
    async_copy16(Ag1, &As[0][2048 + tid * 8]);
    async_copy16(Bg0, &Bs[0][tid * 8]);
    async_copy16(Bg1, &Bs[0][2048 + tid * 8]);

    int p = 0;
    for (int k0 = 0; k0 < K; k0 += 32) {
        __syncthreads();
        if (k0 + 32 < K) {
            const int np = p ^ 1;
            async_copy16(Ag0 + k0 + 32, &As[np][tid * 8]);
            async_copy16(Ag1 + k0 + 32, &As[np][2048 + tid * 8]);
            async_copy16(Bg0 + k0 + 32, &Bs[np][tid * 8]);
            async_copy16(Bg1 + k0 + 32, &Bs[np][2048 + tid * 8]);
        }
        bf16x8 af[4], bfr[4];
#pragma unroll
        for (int i = 0; i < 4; ++i) af[i]  = lds_frag(&As[p][a_off + i * 512]);
#pragma unroll
        for (int j = 0; j < 4; ++j) bfr[j] = lds_frag(&Bs[p][b_off + j * 512]);
#pragma unroll
        for (int i = 0; i < 4; ++i)
#pragma unroll
            for (int j = 0; j < 4; ++j)
                acc[i][j] = __builtin_amdgcn_mfma_f32_16x16x32_bf16(af[i], bfr[j], acc[i][j], 0, 0, 0);
        p ^= 1;
    }

    // C/D layout: col = lane&15, row = (lane>>4)*4 + reg
#pragma unroll
    for (int i = 0; i < 4; ++i)
#pragma unroll
        for (int j = 0; j < 4; ++j) {
            int n = n0 + wc + j * 16 + c;
            int which = n >> 10, h = (n >> 6) & 15, kd = n & 63;
            int m_base = m0 + wr + i * 16 + qd * 4;
            int b = m_base >> 11, l0 = m_base & 2047;
            int bh = b * 16 + h;
            if (which == 2) {
                u32x2 o2;
                o2[0] = pack_bf16(acc[i][j][0], acc[i][j][1]);
                o2[1] = pack_bf16(acc[i][j][2], acc[i][j][3]);
                *(u32x2*)(outb + (size_t)(128 + bh) * 131072 + (size_t)kd * 2048 + l0) = o2;
            } else if (which == 0) {
#pragma unroll
                for (int r = 0; r < 4; ++r)
                    outb[(size_t)bh * 131072 + (size_t)(l0 + r) * 64 + kd] =
                        f2bf(acc[i][j][r] * 0.1803368801f);   // 0.125*log2(e)
            } else {
#pragma unroll
                for (int r = 0; r < 4; ++r)
                    outb[(size_t)(64 + bh) * 131072 + (size_t)(l0 + r) * 64 + kd] =
                        f2bf(acc[i][j][r]);
            }
        }
}

// ---------------------------------------------------------------------------
// Output gemm: C[M,N] fp32 = A[M,K]bf16 * Bt[N,K]^T. 64x128 tile, BK=32,
// double-buffered, swizzled. Grid (8,128) -> 1024 blocks = 4 blocks/CU.
__global__ __launch_bounds__(256) void gemm_out(const u16* __restrict__ A,
                                                const u16* __restrict__ Bt,
                                                float* __restrict__ outf,
                                                int K, int N) {
    __shared__ u16 As[2][64 * 32];
    __shared__ u16 Bs[2][128 * 32];
    const int tid = threadIdx.x;
    const int lane = tid & 63;
    const int wv = tid >> 6;
    const int wr = (wv >> 1) * 32;     // wave row-half: 0 or 32
    const int wc = (wv & 1) * 64;      // wave col-half: 0 or 64
    const int qd = lane >> 4;
    const int c  = lane & 15;
    const int m0 = blockIdx.y * 64;
    const int n0 = blockIdx.x * 128;

    const int srow = tid >> 2;         // 0..63
    const int sg = ((tid & 3) ^ ((srow >> 1) & 3)) << 3;

    const u16* Ag0 = A  + (size_t)(m0 +      srow) * K + sg;   // 64 rows, 1 issue
    const u16* Bg0 = Bt + (size_t)(n0 +      srow) * K + sg;
    const u16* Bg1 = Bt + (size_t)(n0 + 64 + srow) * K + sg;

    const u32 fsw = (qd ^ ((c >> 1) & 3)) << 3;
    const u32 a_off = (wr + c) * 32 + fsw;                 // + i*512
    const u32 b_off = (wc + c) * 32 + fsw;                 // + j*512

    f32x4 acc[2][4] = {};

    async_copy16(Ag0, &As[0][tid * 8]);
    async_copy16(Bg0, &Bs[0][tid * 8]);
    async_copy16(Bg1, &Bs[0][2048 + tid * 8]);

    int p = 0;
    for (int k0 = 0; k0 < K; k0 += 32) {
        __syncthreads();
        if (k0 + 32 < K) {
            const int np = p ^ 1;
            async_copy16(Ag0 + k0 + 32, &As[np][tid * 8]);
            async_copy16(Bg0 + k0 + 32, &Bs[np][tid * 8]);
            async_copy16(Bg1 + k0 + 32, &Bs[np][2048 + tid * 8]);
        }
        bf16x8 af[2], bfr[4];
#pragma unroll
        for (int i = 0; i < 2; ++i) af[i]  = lds_frag(&As[p][a_off + i * 512]);
#pragma unroll
        for (int j = 0; j < 4; ++j) bfr[j] = lds_frag(&Bs[p][b_off + j * 512]);
#pragma unroll
        for (int i = 0; i < 2; ++i)
#pragma unroll
            for (int j = 0; j < 4; ++j)
                acc[i][j] = __builtin_amdgcn_mfma_f32_16x16x32_bf16(af[i], bfr[j], acc[i][j], 0, 0, 0);
        p ^= 1;
    }

#pragma unroll
    for (int i = 0; i < 2; ++i)
#pragma unroll
        for (int j = 0; j < 4; ++j)
#pragma unroll
            for (int r = 0; r < 4; ++r) {
                int m = m0 + wr + i * 16 + qd * 4 + r;
                int n = n0 + wc + j * 16 + c;
                outf[(size_t)m * N + n] = acc[i][j][r];
            }
}

// ---------------------------------------------------------------------------
// Flash attention, causal, S^T form. Round-2 structure:
//  * Frag-level software pipeline: the wave's two q-fragments (a,b) form two
//    independent streams. Program order per tile:
//      issue S_b(kt) MFMAs -> finish_a(kt) exp2/permlane/PV (VALU under MFMAs)
//      -> barrier/copies -> issue S_a(kt+1) MFMAs -> finish_b(kt) (VALU under
//      MFMAs).  Peak S-state = sa+sb = 64 VGPR (round-0 footprint, no spill).
//  * No lambdas/pointers around register arrays (rule-#20: address-taken
//    arrays fall to scratch -- round 1's +25 MB scratch traffic). Macros on
//    named, constant-indexed arrays only.
//  * In-register P^T via v_permlane{32,16}_swap (verified R1), exp2 bias -8
//    folded into MFMA C-init, packed f32x4 row-sums, setprio on MFMA clusters.
//  * K double-buffered, V triple-buffered: LDS = 80 KB -> 2 blocks/CU.
#define ATTN_COMPUTE_S(KSB, QARR, S)                                          \
    do {                                                                      \
        _Pragma("unroll") for (int f = 0; f < 8; ++f)                         \
            S[f] = f32x4{-8.f, -8.f, -8.f, -8.f};                             \
        __builtin_amdgcn_s_setprio(1);                                        \
        _Pragma("unroll") for (int ks = 0; ks < 2; ++ks) {                    \
            const u16* kp = (KSB) + kf_off[ks];                               \
            _Pragma("unroll") for (int f = 0; f < 8; ++f) {                   \
                bf16x8 kf = lds_frag(kp + f * 1024);                          \
                S[f] = __builtin_amdgcn_mfma_f32_16x16x32_bf16(               \
                    kf, QARR[ks], S[f], 0, 0, 0);                             \
            }                                                                 \
        }                                                                     \
        __builtin_amdgcn_s_setprio(0);                                        \
    } while (0)

#define ATTN_FINISH(S, QROW, RV, ACC, VTB, KT)                                \
    do {                                                                      \
        if ((KT) == qt) {                                                     \
            _Pragma("unroll") for (int f = 0; f < 8; ++f)                     \
                _Pragma("unroll") for (int r = 0; r < 4; ++r) {               \
                    int key = (KT) * 128 + f * 16 + qd * 4 + r;               \
                    if (key > (QROW)) S[f][r] = -3e38f;                       \
                }                                                             \
        }                                                                     \
        _Pragma("unroll") for (int f = 0; f < 8; ++f) {                       \
            _Pragma("unroll") for (int r = 0; r < 4; ++r)                     \
                S[f][r] = EXP2(S[f][r]);                                      \
            RV += S[f];                                                       \
        }                                                                     \
        _Pragma("unroll") for (int kc = 0; kc < 4; ++kc) {                    \
            u32 a0 = pack_bf16(S[2 * kc][0], S[2 * kc][1]);                   \
            u32 a1 = pack_bf16(S[2 * kc + 1][0], S[2 * kc + 1][1]);           \
            u32 b0 = pack_bf16(S[2 * kc][2], S[2 * kc][3]);                   \
            u32 b1 = pack_bf16(S[2 * kc + 1][2], S[2 * kc + 1][3]);           \
            permlane32_swap(a0, a1); permlane16_swap(a0, a1);                 \
            permlane32_swap(b0, b1); permlane16_swap(b0, b1);                 \
            u32x4 wpk = {a0, b0, a1, b1};                                     \
            bf16x8 pfrag = __builtin_bit_cast(bf16x8, wpk);                   \
            const u16* vp = (VTB) + vf_off[kc];                               \
            __builtin_amdgcn_s_setprio(1);                                    \
            _Pragma("unroll") for (int jo = 0; jo < 4; ++jo) {                \
                bf16x8 vf = lds_frag(vp + jo * 2048);                         \
                ACC[jo] = __builtin_amdgcn_mfma_f32_16x16x32_bf16(            \
                    vf, pfrag, ACC[jo], 0, 0, 0);                             \
            }                                                                 \
            __builtin_amdgcn_s_setprio(0);                                    \
        }                                                                     \
    } while (0)

__global__ __launch_bounds__(256, 2) void attn_kernel(const u16* __restrict__ qkv,
                                                      u16* __restrict__ att) {
    __shared__ u16 Ks[2][128 * 64];   // [key][kd], 16B-chunk XOR swizzled
    __shared__ u16 Vt[3][64 * 128];   // [kd][key], 16B-chunk XOR swizzled

    const int tid = threadIdx.x;
    const int lane = tid & 63;
    const int w = tid >> 6;
    const int qd = lane >> 4;
    const int c = lane & 15;

    // XCD swizzle: flat%8 == bh%8 -> one bh's K/V stays in one XCD L2
    const int flat = blockIdx.x + 8 * blockIdx.y;
    const int bh = (flat & 7) + 8 * ((flat >> 3) & 7);
    const int bx = flat >> 6;
    const int b = bh >> 4, h = bh & 15;

    const u16* Qg = qkv + (size_t)bh * 131072;
    const u16* Kg = qkv + (size_t)(64 + bh) * 131072;
    const u16* Vg = qkv + (size_t)(128 + bh) * 131072;   // [kd][2048]

    u32 kf_off[2];
#pragma unroll
    for (int ks = 0; ks < 2; ++ks)
        kf_off[ks] = c * 64 + (((ks * 4 + qd) ^ (c & 7)) << 3);
    u32 vf_off[4];
#pragma unroll
    for (int kc = 0; kc < 4; ++kc)
        vf_off[kc] = c * 128 + (((kc * 4 + qd) ^ c) << 3);

    // 8 x 16B async copies per tile (K and V), pre-swizzled global source,
    // linear LDS dest (global_load_lds requirement). Writes LDS only.
    auto issue_copy = [&](int t, u16* kd, u16* vd) {
#pragma unroll
        for (int it = 0; it < 4; ++it) {
            int lin = it * 256 + tid;
            int krw = lin >> 3, kch = lin & 7;
            int vrw = lin >> 4, vch = lin & 15;
            async_copy16(Kg + (size_t)t * 8192 + krw * 64 + ((kch ^ (krw & 7)) << 3),
                         kd + lin * 8);
            async_copy16(Vg + (size_t)t * 128 + (size_t)vrw * 2048 + ((vch ^ (vrw & 15)) << 3),
                         vd + lin * 8);
        }
    };

#pragma unroll 1
    for (int seg = 0; seg < 2; ++seg) {
        const int qt = seg ? (15 - bx) : bx;            // balanced causal pairing
        const int qa_row = qt * 128 + w * 32 + c;       // frag a
        const int qb_row = qa_row + 16;                 // frag b

        bf16x8 qa[2], qb[2];
#pragma unroll
        for (int ks = 0; ks < 2; ++ks) {
            qa[ks] = *(const bf16x8*)(Qg + (size_t)qa_row * 64 + ks * 32 + qd * 8);
            qb[ks] = *(const bf16x8*)(Qg + (size_t)qb_row * 64 + ks * 32 + qd * 8);
        }

        f32x4 acca[4] = {}, accb[4] = {};
        f32x4 rva = {}, rvb = {};                        // packed row-sum accum
        f32x4 sa[8], sb[8];                              // ONE S set per frag

        const int nkt = qt + 1;

        // ---- prologue: tile 0 staged, tile 1 in flight, S_a(0) issued ----
        __syncthreads();                     // prev-seg readers done
        issue_copy(0, Ks[0], Vt[0]);
        __syncthreads();                     // tile 0 ready (all waves)
        if (nkt > 1) issue_copy(1, Ks[1], Vt[1]);
        ATTN_COMPUTE_S(Ks[0], qa, sa);

        u16 *vPV = Vt[0], *vNx = Vt[1], *vFr = Vt[2];

#pragma unroll 1
        for (int kt = 0; kt < nkt; ++kt) {
            ATTN_COMPUTE_S(Ks[kt & 1], qb, sb);          // S_b(kt) in flight
            ATTN_FINISH(sa, qa_row, rva, acca, vPV, kt); // exp2 under S_b MFMAs
            if (kt + 1 < nkt) {
                __syncthreads();                         // tile kt+1 ready
                if (kt + 2 < nkt) issue_copy(kt + 2, Ks[kt & 1], vFr);
                ATTN_COMPUTE_S(Ks[(kt + 1) & 1], qa, sa); // S_a(kt+1) in flight
            }
            ATTN_FINISH(sb, qb_row, rvb, accb, vPV, kt); // exp2 under S_a MFMAs
            u16* t0 = vPV; vPV = vNx; vNx = vFr; vFr = t0;
        }

        // epilogue: reduce row-sums across the 4 quad-groups, then scale
        float ra = rva[0] + rva[1] + rva[2] + rva[3];
        float rb = rvb[0] + rvb[1] + rvb[2] + rvb[3];
        ra += __shfl_xor(ra, 16, 64);
        ra += __shfl_xor(ra, 32, 64);
        rb += __shfl_xor(rb, 16, 64);
        rb += __shfl_xor(rb, 32, 64);
        float ia = __builtin_amdgcn_rcpf(ra), ib = __builtin_amdgcn_rcpf(rb);
        u16* ar = att + ((size_t)b * 2048 + qa_row) * 1024 + h * 64;
        u16* br = att + ((size_t)b * 2048 + qb_row) * 1024 + h * 64;
#pragma unroll
        for (int jo = 0; jo < 4; ++jo) {
            u32x2 oa, ob;
            oa[0] = pack_bf16(acca[jo][0] * ia, acca[jo][1] * ia);
            oa[1] = pack_bf16(acca[jo][2] * ia, acca[jo][3] * ia);
            ob[0] = pack_bf16(accb[jo][0] * ib, accb[jo][1] * ib);
            ob[1] = pack_bf16(accb[jo][2] * ib, accb[jo][3] * ib);
            *(u32x2*)(ar + jo * 16 + qd * 4) = oa;
            *(u32x2*)(br + jo * 16 + qd * 4) = ob;
        }
    }
}

// ---------------------------------------------------------------------------
extern "C" void kernel_launch(void* const* d_in, const int* in_sizes, int n_in,
                              void* d_out, int out_size, void* d_ws, size_t ws_size,
                              hipStream_t stream) {
    const float* x    = (const float*)d_in[0];   // [4,2048,1024]
    const float* Wqkv = (const float*)d_in[1];   // [1024,3072]
    const float* Wout = (const float*)d_in[2];   // [1024,1024]
    float* out = (float*)d_out;                  // [4,2048,1024] fp32

    char* ws = (char*)d_ws;
    u16* x_bf   = (u16*)(ws);                    // 16 MB
    u16* wqkv_t = (u16*)(ws + 16777216);         // 6 MB   [3072][1024]
    u16* wout_t = (u16*)(ws + 23068672);         // 2 MB   [1024][1024]
    u16* qkv_h  = (u16*)(ws + 25165824);         // 48 MB  Q,K [bh][l][64], V^T [bh][kd][2048]
    u16* att    = (u16*)(ws + 75497472);         // 16 MB  [4][2048][1024]

    prep<<<dim3(5120), dim3(256), 0, stream>>>(x, Wqkv, Wout, x_bf, wqkv_t, wout_t);
    gemm_qkv<<<dim3(24, 64), dim3(256), 0, stream>>>(x_bf, wqkv_t, qkv_h, 1024, 3072);
    attn_kernel<<<dim3(8, 64), dim3(256), 0, stream>>>(qkv_h, att);
    gemm_out<<<dim3(8, 128), dim3(256), 0, stream>>>(att, wout_t, out, 1024, 1024);
}

// Round 3
// 246.174 us; speedup vs baseline: 1.0976x; 1.0169x over previous
//
#include <hip/hip_runtime.h>

typedef unsigned short u16;
typedef unsigned int   u32;
typedef __bf16   bf16x8 __attribute__((ext_vector_type(8)));
typedef float    f32x4  __attribute__((ext_vector_type(4)));
typedef u16      u16x4  __attribute__((ext_vector_type(4)));
typedef u16      u16x8  __attribute__((ext_vector_type(8)));
typedef u32      u32x2  __attribute__((ext_vector_type(2)));
typedef u32      u32x4  __attribute__((ext_vector_type(4)));

#if __has_builtin(__builtin_amdgcn_exp2f)
#define EXP2(x) __builtin_amdgcn_exp2f(x)
#else
#define EXP2(x) exp2f(x)
#endif

// fp32 -> bf16 round-to-nearest-even
__device__ __forceinline__ u16 f2bf(float f) {
    unsigned u = __float_as_uint(f);
    u += 0x7FFFu + ((u >> 16) & 1u);
    return (u16)(u >> 16);
}

__device__ __forceinline__ u32 pack_bf16(float a, float b) {
#if __has_builtin(__builtin_amdgcn_cvt_pk_bf16_f32)
    typedef __bf16 bf16x2 __attribute__((ext_vector_type(2)));
    bf16x2 r = __builtin_amdgcn_cvt_pk_bf16_f32(a, b);
    return __builtin_bit_cast(u32, r);
#else
    return (u32)f2bf(a) | ((u32)f2bf(b) << 16);
#endif
}

// async global->LDS, 16 bytes/lane. LDS dest = wave-uniform base + lane*16.
__device__ __forceinline__ void async_copy16(const u16* g, u16* l) {
    __builtin_amdgcn_global_load_lds(
        (const __attribute__((address_space(1))) unsigned*)g,
        (__attribute__((address_space(3))) unsigned*)l, 16, 0, 0);
}

__device__ __forceinline__ bf16x8 lds_frag(const u16* p) {
    return *(const bf16x8*)p;
}

// gfx950 cross-lane swaps (both operands read-write).
__device__ __forceinline__ void permlane32_swap(u32& a, u32& b) {
    asm("v_permlane32_swap_b32 %0, %1" : "+v"(a), "+v"(b));
}
__device__ __forceinline__ void permlane16_swap(u32& a, u32& b) {
    asm("v_permlane16_swap_b32 %0, %1" : "+v"(a), "+v"(b));
}

// ---------------------------------------------------------------------------
// Fused prep: blocks [0,768) transpose Wqkv, [768,1024) transpose Wout,
// [1024,5120) convert x to bf16 (16 elems/thread).
__global__ __launch_bounds__(256) void prep(const float* __restrict__ x,
                                            const float* __restrict__ Wqkv,
                                            const float* __restrict__ Wout,
                                            u16* __restrict__ xb,
                                            u16* __restrict__ wqkv_t,
                                            u16* __restrict__ wout_t) {
    __shared__ u16 t[64 * 72];
    const int bid = blockIdx.x;
    const int tid = threadIdx.x;

    if (bid >= 1024) {
        // x fp32 -> bf16
        size_t i = ((size_t)(bid - 1024) * 256 + tid) * 8;
        float4 v0 = *(const float4*)(x + i);
        float4 v1 = *(const float4*)(x + i + 4);
        u16x8 o = { f2bf(v0.x), f2bf(v0.y), f2bf(v0.z), f2bf(v0.w),
                    f2bf(v1.x), f2bf(v1.y), f2bf(v1.z), f2bf(v1.w) };
        *(u16x8*)(xb + i) = o;
        return;
    }

    // W fp32 [Kd][Nd] -> Wt bf16 [Nd][Kd]
    const float* W;  u16* Wt;  int Kd, Nd, n0, k0;
    if (bid < 768) { W = Wqkv; Wt = wqkv_t; Kd = 1024; Nd = 3072;
                     n0 = (bid % 48) * 64; k0 = (bid / 48) * 64; }
    else           { W = Wout; Wt = wout_t; Kd = 1024; Nd = 1024;
                     n0 = ((bid - 768) % 16) * 64; k0 = ((bid - 768) / 16) * 64; }
#pragma unroll
    for (int i = 0; i < 4; ++i) {
        int lin = i * 256 + tid;
        int kr = lin >> 4, nc = (lin & 15) << 2;
        float4 v = *(const float4*)(W + (size_t)(k0 + kr) * Nd + n0 + nc);
        u16x4 o = { f2bf(v.x), f2bf(v.y), f2bf(v.z), f2bf(v.w) };
        *(u16x4*)&t[kr * 72 + nc] = o;
    }
    __syncthreads();
#pragma unroll
    for (int i = 0; i < 2; ++i) {
        int lin = i * 256 + tid;
        int nr = lin >> 3, kc = (lin & 7) << 3;
        u16x8 o;
#pragma unroll
        for (int jj = 0; jj < 8; ++jj) o[jj] = t[(kc + jj) * 72 + nr];
        *(u16x8*)(Wt + (size_t)(n0 + nr) * Kd + k0 + kc) = o;
    }
}

// ---------------------------------------------------------------------------
// QKV gemm: C[M,N] = A[M,K] * Bt[N,K]^T, 128x128 tile, BK=32, double-buffered
// (one barrier/iter), LDS chunk-XOR swizzle (conflict-free, verified R6).
// Scatter epilogue: Q (scaled by 0.125*log2e) [bh][l][64], K [bh][l][64],
// V transposed [bh][kd][2048].
__global__ __launch_bounds__(256) void gemm_qkv(const u16* __restrict__ A,
                                                const u16* __restrict__ Bt,
                                                u16* __restrict__ outb,
                                                int K, int N) {
    __shared__ u16 As[2][128 * 32];
    __shared__ u16 Bs[2][128 * 32];
    const int tid = threadIdx.x;
    const int lane = tid & 63;
    const int wv = tid >> 6;
    const int wr = (wv >> 1) * 64;
    const int wc = (wv & 1) * 64;
    const int qd = lane >> 4;
    const int c  = lane & 15;
    const int m0 = blockIdx.y * 128;
    const int n0 = blockIdx.x * 128;

    const int srow = tid >> 2;
    const int sg = ((tid & 3) ^ ((srow >> 1) & 3)) << 3;   // swizzled source chunk

    const u16* Ag0 = A  + (size_t)(m0 +      srow) * K + sg;
    const u16* Ag1 = A  + (size_t)(m0 + 64 + srow) * K + sg;
    const u16* Bg0 = Bt + (size_t)(n0 +      srow) * K + sg;
    const u16* Bg1 = Bt + (size_t)(n0 + 64 + srow) * K + sg;

    const u32 fsw = (qd ^ ((c >> 1) & 3)) << 3;            // swizzled frag chunk
    const u32 a_off = (wr + c) * 32 + fsw;                 // + i*512
    const u32 b_off = (wc + c) * 32 + fsw;                 // + j*512

    f32x4 acc[4][4] = {};

    async_copy16(Ag0, &As[0][tid * 8]);
    async_copy16(Ag1, &As[0][2048 + tid * 8]);
    async_copy16(Bg0, &Bs[0][tid * 8]);
    async_copy16(Bg1, &Bs[0][2048 + tid * 8]);

    int p = 0;
    for (int k0 = 0; k0 < K; k0 += 32) {
        __syncthreads();
        if (k0 + 32 < K) {
            const int np = p ^ 1;
            async_copy16(Ag0 + k0 + 32, &As[np][tid * 8]);
            async_copy16(Ag1 + k0 + 32, &As[np][2048 + tid * 8]);
            async_copy16(Bg0 + k0 + 32, &Bs[np][tid * 8]);
            async_copy16(Bg1 + k0 + 32, &Bs[np][2048 + tid * 8]);
        }
        bf16x8 af[4], bfr[4];
#pragma unroll
        for (int i = 0; i < 4; ++i) af[i]  = lds_frag(&As[p][a_off + i * 512]);
#pragma unroll
        for (int j = 0; j < 4; ++j) bfr[j] = lds_frag(&Bs[p][b_off + j * 512]);
#pragma unroll
        for (int i = 0; i < 4; ++i)
#pragma unroll
            for (int j = 0; j < 4; ++j)
                acc[i][j] = __builtin_amdgcn_mfma_f32_16x16x32_bf16(af[i], bfr[j], acc[i][j], 0, 0, 0);
        p ^= 1;
    }

    // C/D layout: col = lane&15, row = (lane>>4)*4 + reg
#pragma unroll
    for (int i = 0; i < 4; ++i)
#pragma unroll
        for (int j = 0; j < 4; ++j) {
            int n = n0 + wc + j * 16 + c;
            int which = n >> 10, h = (n >> 6) & 15, kd = n & 63;
            int m_base = m0 + wr + i * 16 + qd * 4;
            int b = m_base >> 11, l0 = m_base & 2047;
            int bh = b * 16 + h;
            if (which == 2) {
                u32x2 o2;
                o2[0] = pack_bf16(acc[i][j][0], acc[i][j][1]);
                o2[1] = pack_bf16(acc[i][j][2], acc[i][j][3]);
                *(u32x2*)(outb + (size_t)(128 + bh) * 131072 + (size_t)kd * 2048 + l0) = o2;
            } else if (which == 0) {
#pragma unroll
                for (int r = 0; r < 4; ++r)
                    outb[(size_t)bh * 131072 + (size_t)(l0 + r) * 64 + kd] =
                        f2bf(acc[i][j][r] * 0.1803368801f);   // 0.125*log2(e)
            } else {
#pragma unroll
                for (int r = 0; r < 4; ++r)
                    outb[(size_t)(64 + bh) * 131072 + (size_t)(l0 + r) * 64 + kd] =
                        f2bf(acc[i][j][r]);
            }
        }
}

// ---------------------------------------------------------------------------
// Output gemm: C[M,N] fp32 = A[M,K]bf16 * Bt[N,K]^T. 64x128 tile, BK=32,
// double-buffered, swizzled. Grid (8,128) -> 1024 blocks = 4 blocks/CU.
__global__ __launch_bounds__(256) void gemm_out(const u16* __restrict__ A,
                                                const u16* __restrict__ Bt,
                                                float* __restrict__ outf,
                                                int K, int N) {
    __shared__ u16 As[2][64 * 32];
    __shared__ u16 Bs[2][128 * 32];
    const int tid = threadIdx.x;
    const int lane = tid & 63;
    const int wv = tid >> 6;
    const int wr = (wv >> 1) * 32;     // wave row-half: 0 or 32
    const int wc = (wv & 1) * 64;      // wave col-half: 0 or 64
    const int qd = lane >> 4;
    const int c  = lane & 15;
    const int m0 = blockIdx.y * 64;
    const int n0 = blockIdx.x * 128;

    const int srow = tid >> 2;         // 0..63
    const int sg = ((tid & 3) ^ ((srow >> 1) & 3)) << 3;

    const u16* Ag0 = A  + (size_t)(m0 +      srow) * K + sg;   // 64 rows, 1 issue
    const u16* Bg0 = Bt + (size_t)(n0 +      srow) * K + sg;
    const u16* Bg1 = Bt + (size_t)(n0 + 64 + srow) * K + sg;

    const u32 fsw = (qd ^ ((c >> 1) & 3)) << 3;
    const u32 a_off = (wr + c) * 32 + fsw;                 // + i*512
    const u32 b_off = (wc + c) * 32 + fsw;                 // + j*512

    f32x4 acc[2][4] = {};

    async_copy16(Ag0, &As[0][tid * 8]);
    async_copy16(Bg0, &Bs[0][tid * 8]);
    async_copy16(Bg1, &Bs[0][2048 + tid * 8]);

    int p = 0;
    for (int k0 = 0; k0 < K; k0 += 32) {
        __syncthreads();
        if (k0 + 32 < K) {
            const int np = p ^ 1;
            async_copy16(Ag0 + k0 + 32, &As[np][tid * 8]);
            async_copy16(Bg0 + k0 + 32, &Bs[np][tid * 8]);
            async_copy16(Bg1 + k0 + 32, &Bs[np][2048 + tid * 8]);
        }
        bf16x8 af[2], bfr[4];
#pragma unroll
        for (int i = 0; i < 2; ++i) af[i]  = lds_frag(&As[p][a_off + i * 512]);
#pragma unroll
        for (int j = 0; j < 4; ++j) bfr[j] = lds_frag(&Bs[p][b_off + j * 512]);
#pragma unroll
        for (int i = 0; i < 2; ++i)
#pragma unroll
            for (int j = 0; j < 4; ++j)
                acc[i][j] = __builtin_amdgcn_mfma_f32_16x16x32_bf16(af[i], bfr[j], acc[i][j], 0, 0, 0);
        p ^= 1;
    }

#pragma unroll
    for (int i = 0; i < 2; ++i)
#pragma unroll
        for (int j = 0; j < 4; ++j)
#pragma unroll
            for (int r = 0; r < 4; ++r) {
                int m = m0 + wr + i * 16 + qd * 4 + r;
                int n = n0 + wc + j * 16 + c;
                outf[(size_t)m * N + n] = acc[i][j][r];
            }
}

// ---------------------------------------------------------------------------
// Flash attention, causal, S^T form. Round-3 structure:
//  * FUSED a/b streams: each K fragment read feeds BOTH sa and sb MFMAs; each
//    V fragment read feeds BOTH acca and accb. LDS reads 64 -> 32 per
//    wave/tile (R2's frag-pipeline doubled K/V reads; LDS read port was ~60%
//    of the wall). Cross-wave overlap (2 waves/SIMD + setprio) replaces the
//    within-wave pipeline.
//  * In-register P^T via v_permlane{32,16}_swap (verified R1/R2), exp2 bias
//    -8 folded into MFMA C-init, packed f32x4 row-sums.
//  * No address-taken register arrays (rule #20): macros on named,
//    constant-indexed arrays only.
//  * K,V double-buffered: LDS = 64 KB -> 2 blocks/CU; one barrier per tile.
#define ATTN_S_AB(KSB)                                                        \
    do {                                                                      \
        _Pragma("unroll") for (int f = 0; f < 8; ++f) {                       \
            sa[f] = f32x4{-8.f, -8.f, -8.f, -8.f};                            \
            sb[f] = f32x4{-8.f, -8.f, -8.f, -8.f};                            \
        }                                                                     \
        __builtin_amdgcn_s_setprio(1);                                        \
        _Pragma("unroll") for (int ks = 0; ks < 2; ++ks) {                    \
            const u16* kp = (KSB) + kf_off[ks];                               \
            _Pragma("unroll") for (int f = 0; f < 8; ++f) {                   \
                bf16x8 kf = lds_frag(kp + f * 1024);                          \
                sa[f] = __builtin_amdgcn_mfma_f32_16x16x32_bf16(              \
                    kf, qa[ks], sa[f], 0, 0, 0);                              \
                sb[f] = __builtin_amdgcn_mfma_f32_16x16x32_bf16(              \
                    kf, qb[ks], sb[f], 0, 0, 0);                              \
            }                                                                 \
        }                                                                     \
        __builtin_amdgcn_s_setprio(0);                                        \
    } while (0)

#define ATTN_FINISH_AB(VTB, KT)                                               \
    do {                                                                      \
        if ((KT) == qt) {                                                     \
            _Pragma("unroll") for (int f = 0; f < 8; ++f)                     \
                _Pragma("unroll") for (int r = 0; r < 4; ++r) {               \
                    int key = (KT) * 128 + f * 16 + qd * 4 + r;               \
                    if (key > qa_row) sa[f][r] = -3e38f;                      \
                    if (key > qb_row) sb[f][r] = -3e38f;                      \
                }                                                             \
        }                                                                     \
        _Pragma("unroll") for (int f = 0; f < 8; ++f) {                       \
            _Pragma("unroll") for (int r = 0; r < 4; ++r) {                   \
                sa[f][r] = EXP2(sa[f][r]);                                    \
                sb[f][r] = EXP2(sb[f][r]);                                    \
            }                                                                 \
            rva += sa[f];                                                     \
            rvb += sb[f];                                                     \
        }                                                                     \
        _Pragma("unroll") for (int kc = 0; kc < 4; ++kc) {                    \
            u32 a0 = pack_bf16(sa[2 * kc][0], sa[2 * kc][1]);                 \
            u32 a1 = pack_bf16(sa[2 * kc + 1][0], sa[2 * kc + 1][1]);         \
            u32 b0 = pack_bf16(sa[2 * kc][2], sa[2 * kc][3]);                 \
            u32 b1 = pack_bf16(sa[2 * kc + 1][2], sa[2 * kc + 1][3]);         \
            permlane32_swap(a0, a1); permlane16_swap(a0, a1);                 \
            permlane32_swap(b0, b1); permlane16_swap(b0, b1);                 \
            u32x4 wpa = {a0, b0, a1, b1};                                     \
            bf16x8 pa = __builtin_bit_cast(bf16x8, wpa);                      \
            u32 c0 = pack_bf16(sb[2 * kc][0], sb[2 * kc][1]);                 \
            u32 c1 = pack_bf16(sb[2 * kc + 1][0], sb[2 * kc + 1][1]);         \
            u32 d0 = pack_bf16(sb[2 * kc][2], sb[2 * kc][3]);                 \
            u32 d1 = pack_bf16(sb[2 * kc + 1][2], sb[2 * kc + 1][3]);         \
            permlane32_swap(c0, c1); permlane16_swap(c0, c1);                 \
            permlane32_swap(d0, d1); permlane16_swap(d0, d1);                 \
            u32x4 wpb = {c0, d0, c1, d1};                                     \
            bf16x8 pb = __builtin_bit_cast(bf16x8, wpb);                      \
            const u16* vp = (VTB) + vf_off[kc];                               \
            __builtin_amdgcn_s_setprio(1);                                    \
            _Pragma("unroll") for (int jo = 0; jo < 4; ++jo) {                \
                bf16x8 vf = lds_frag(vp + jo * 2048);                         \
                acca[jo] = __builtin_amdgcn_mfma_f32_16x16x32_bf16(           \
                    vf, pa, acca[jo], 0, 0, 0);                               \
                accb[jo] = __builtin_amdgcn_mfma_f32_16x16x32_bf16(           \
                    vf, pb, accb[jo], 0, 0, 0);                               \
            }                                                                 \
            __builtin_amdgcn_s_setprio(0);                                    \
        }                                                                     \
    } while (0)

__global__ __launch_bounds__(256, 2) void attn_kernel(const u16* __restrict__ qkv,
                                                      u16* __restrict__ att) {
    __shared__ u16 Ks[2][128 * 64];   // [key][kd], 16B-chunk XOR swizzled
    __shared__ u16 Vt[2][64 * 128];   // [kd][key], 16B-chunk XOR swizzled

    const int tid = threadIdx.x;
    const int lane = tid & 63;
    const int w = tid >> 6;
    const int qd = lane >> 4;
    const int c = lane & 15;

    // XCD swizzle: flat%8 == bh%8 -> one bh's K/V stays in one XCD L2
    const int flat = blockIdx.x + 8 * blockIdx.y;
    const int bh = (flat & 7) + 8 * ((flat >> 3) & 7);
    const int bx = flat >> 6;
    const int b = bh >> 4, h = bh & 15;

    const u16* Qg = qkv + (size_t)bh * 131072;
    const u16* Kg = qkv + (size_t)(64 + bh) * 131072;
    const u16* Vg = qkv + (size_t)(128 + bh) * 131072;   // [kd][2048]

    u32 kf_off[2];
#pragma unroll
    for (int ks = 0; ks < 2; ++ks)
        kf_off[ks] = c * 64 + (((ks * 4 + qd) ^ (c & 7)) << 3);
    u32 vf_off[4];
#pragma unroll
    for (int kc = 0; kc < 4; ++kc)
        vf_off[kc] = c * 128 + (((kc * 4 + qd) ^ c) << 3);

    // 8 x 16B async copies per tile (K and V), pre-swizzled global source,
    // linear LDS dest (global_load_lds requirement). Writes LDS only.
    auto issue_copy = [&](int t, u16* kd, u16* vd) {
#pragma unroll
        for (int it = 0; it < 4; ++it) {
            int lin = it * 256 + tid;
            int krw = lin >> 3, kch = lin & 7;
            int vrw = lin >> 4, vch = lin & 15;
            async_copy16(Kg + (size_t)t * 8192 + krw * 64 + ((kch ^ (krw & 7)) << 3),
                         kd + lin * 8);
            async_copy16(Vg + (size_t)t * 128 + (size_t)vrw * 2048 + ((vch ^ (vrw & 15)) << 3),
                         vd + lin * 8);
        }
    };

#pragma unroll 1
    for (int seg = 0; seg < 2; ++seg) {
        const int qt = seg ? (15 - bx) : bx;            // balanced causal pairing
        const int qa_row = qt * 128 + w * 32 + c;       // frag a
        const int qb_row = qa_row + 16;                 // frag b

        bf16x8 qa[2], qb[2];
#pragma unroll
        for (int ks = 0; ks < 2; ++ks) {
            qa[ks] = *(const bf16x8*)(Qg + (size_t)qa_row * 64 + ks * 32 + qd * 8);
            qb[ks] = *(const bf16x8*)(Qg + (size_t)qb_row * 64 + ks * 32 + qd * 8);
        }

        f32x4 acca[4] = {}, accb[4] = {};
        f32x4 rva = {}, rvb = {};                        // packed row-sum accum
        f32x4 sa[8], sb[8];

        const int nkt = qt + 1;

        // ---- prologue: tile 0 staged; tile 1 issued ----
        __syncthreads();                     // prev-seg readers done with bufs
        issue_copy(0, Ks[0], Vt[0]);
        __syncthreads();                     // tile 0 landed (all waves)
        if (nkt > 1) issue_copy(1, Ks[1], Vt[1]);

#pragma unroll 1
        for (int kt = 0; kt < nkt; ++kt) {
            const int p = kt & 1;
            ATTN_S_AB(Ks[p]);                // 32 MFMA, 16 shared kf reads
            ATTN_FINISH_AB(Vt[p], kt);       // exp2/permlane + 32 MFMA, 16 vf reads
            if (kt + 1 < nkt) {
                __syncthreads();             // tile kt+1 landed; buf p free
                if (kt + 2 < nkt) issue_copy(kt + 2, Ks[p], Vt[p]);
            }
        }

        // epilogue: reduce row-sums across the 4 quad-groups, then scale
        float ra = rva[0] + rva[1] + rva[2] + rva[3];
        float rb = rvb[0] + rvb[1] + rvb[2] + rvb[3];
        ra += __shfl_xor(ra, 16, 64);
        ra += __shfl_xor(ra, 32, 64);
        rb += __shfl_xor(rb, 16, 64);
        rb += __shfl_xor(rb, 32, 64);
        float ia = __builtin_amdgcn_rcpf(ra), ib = __builtin_amdgcn_rcpf(rb);
        u16* ar = att + ((size_t)b * 2048 + qa_row) * 1024 + h * 64;
        u16* br = att + ((size_t)b * 2048 + qb_row) * 1024 + h * 64;
#pragma unroll
        for (int jo = 0; jo < 4; ++jo) {
            u32x2 oa, ob;
            oa[0] = pack_bf16(acca[jo][0] * ia, acca[jo][1] * ia);
            oa[1] = pack_bf16(acca[jo][2] * ia, acca[jo][3] * ia);
            ob[0] = pack_bf16(accb[jo][0] * ib, accb[jo][1] * ib);
            ob[1] = pack_bf16(accb[jo][2] * ib, accb[jo][3] * ib);
            *(u32x2*)(ar + jo * 16 + qd * 4) = oa;
            *(u32x2*)(br + jo * 16 + qd * 4) = ob;
        }
    }
}

// ---------------------------------------------------------------------------
extern "C" void kernel_launch(void* const* d_in, const int* in_sizes, int n_in,
                              void* d_out, int out_size, void* d_ws, size_t ws_size,
                              hipStream_t stream) {
    const float* x    = (const float*)d_in[0];   // [4,2048,1024]
    const float* Wqkv = (const float*)d_in[1];   // [1024,3072]
    const float* Wout = (const float*)d_in[2];   // [1024,1024]
    float* out = (float*)d_out;                  // [4,2048,1024] fp32

    char* ws = (char*)d_ws;
    u16* x_bf   = (u16*)(ws);                    // 16 MB
    u16* wqkv_t = (u16*)(ws + 16777216);         // 6 MB   [3072][1024]
    u16* wout_t = (u16*)(ws + 23068672);         // 2 MB   [1024][1024]
    u16* qkv_h  = (u16*)(ws + 25165824);         // 48 MB  Q,K [bh][l][64], V^T [bh][kd][2048]
    u16* att    = (u16*)(ws + 75497472);         // 16 MB  [4][2048][1024]

    prep<<<dim3(5120), dim3(256), 0, stream>>>(x, Wqkv, Wout, x_bf, wqkv_t, wout_t);
    gemm_qkv<<<dim3(24, 64), dim3(256), 0, stream>>>(x_bf, wqkv_t, qkv_h, 1024, 3072);
    attn_kernel<<<dim3(8, 64), dim3(256), 0, stream>>>(qkv_h, att);
    gemm_out<<<dim3(8, 128), dim3(256), 0, stream>>>(att, wout_t, out, 1024, 1024);
}